// Round 2
// baseline (972.996 us; speedup 1.0000x reference)
//
#include <hip/hip_runtime.h>

// RNN: B=1024, T=512, E=64, H=128, OUT=2, VOCAB=4411
// Fused embedding + input proj + tanh recurrence + linear head.
// R2: half-row split. 256 threads/block, thread (j = tid>>1, p = tid&1) owns
// HALF of hidden unit j's weights: w_hh[64] + w_ih[32] = 96 VGPRs -> compiler
// keeps them resident (R1's full-row 192-reg demand was rejected; VGPR=128
// with in-loop weight reloads => 2.3x extra VALU issue). Halves combine with
// one __shfl_xor (pair is always intra-wave). h broadcast via LDS, double-
// buffered, 1 barrier/step.

constexpr int Bc   = 1024;
constexpr int Tc   = 512;
constexpr int Ec   = 64;
constexpr int Hc   = 128;
constexpr int OUTc = 2;

__global__ __launch_bounds__(256, 2) void rnn_fused(
    const int* __restrict__ inputs,      // [B, T]
    const float* __restrict__ emb_table, // [VOCAB, E]
    const float* __restrict__ W_ih,      // [H, E]
    const float* __restrict__ W_hh,      // [H, H]
    const float* __restrict__ b_ih,      // [H]
    const float* __restrict__ b_hh,      // [H]
    const float* __restrict__ W_lin,     // [OUT, H]
    const float* __restrict__ b_lin,     // [OUT]
    float* __restrict__ out)             // [B, OUT]
{
    const int tid = threadIdx.x;   // 0..255
    const int j   = tid >> 1;      // hidden unit 0..127
    const int p   = tid & 1;       // which half of the row
    const int row = blockIdx.x;

    __shared__ float h_buf[2][Hc];
    __shared__ int   toks[Tc];
    __shared__ float red[OUTc][Hc];

    // Coalesced token load for this row (2 KB).
    for (int i = tid; i < Tc; i += 256) toks[i] = inputs[row * Tc + i];

    // Half-row weights in registers: 64 + 32 = 96 VGPRs.
    float w_hh[Hc / 2];
    float w_ih[Ec / 2];
    {
        const float* src = W_hh + j * Hc + p * (Hc / 2);
#pragma unroll
        for (int k = 0; k < Hc / 2; k += 4)
            *(float4*)&w_hh[k] = *(const float4*)(src + k);
    }
    {
        const float* src = W_ih + j * Ec + p * (Ec / 2);
#pragma unroll
        for (int k = 0; k < Ec / 2; k += 4)
            *(float4*)&w_ih[k] = *(const float4*)(src + k);
    }

    const float bias = b_ih[j] + b_hh[j];

    if (tid < Hc) h_buf[0][tid] = 0.0f;
    __syncthreads();

    const int eoff = p * (Ec / 2);
    const int hoff = p * (Hc / 2);

    int   cur = 0;
    float hn  = 0.0f;
    for (int t = 0; t < Tc; ++t) {
        const float* erow = emb_table + (long)toks[t] * Ec + eoff;

        float a0 = 0.0f, a1 = 0.0f, a2 = 0.0f, a3 = 0.0f;

        // Input-projection half: broadcast global reads (L1/L2-hot, 2 addrs/wave).
#pragma unroll
        for (int k = 0; k < Ec / 2; k += 4) {
            const float4 e = *(const float4*)(erow + k);
            a0 = fmaf(e.x, w_ih[k + 0], a0);
            a1 = fmaf(e.y, w_ih[k + 1], a1);
            a2 = fmaf(e.z, w_ih[k + 2], a2);
            a3 = fmaf(e.w, w_ih[k + 3], a3);
        }

        // Recurrence half: broadcast LDS reads (2 addrs/wave, same bank = free 2-way).
        const float* hb = &h_buf[cur][hoff];
#pragma unroll
        for (int k = 0; k < Hc / 2; k += 4) {
            const float4 hv = *(const float4*)(hb + k);
            a0 = fmaf(hv.x, w_hh[k + 0], a0);
            a1 = fmaf(hv.y, w_hh[k + 1], a1);
            a2 = fmaf(hv.z, w_hh[k + 2], a2);
            a3 = fmaf(hv.w, w_hh[k + 3], a3);
        }

        float acc = (a0 + a1) + (a2 + a3);
        acc += __shfl_xor(acc, 1);     // combine the two halves (intra-wave pair)
        const float z = acc + bias;

        // tanh(z) = 1 - 2/(exp(2z)+1); exact at saturation. Both lanes compute
        // (branchless) and both write the same value to h_buf[nxt][j].
        const float ex = __expf(2.0f * z);
        hn = 1.0f - 2.0f / (ex + 1.0f);

        cur ^= 1;
        h_buf[cur][j] = hn;
        __syncthreads();
    }

    // Linear head: out[row][o] = sum_j h[j] * W_lin[o][j] + b_lin[o]
    red[p][j] = hn * W_lin[p * Hc + j];
    __syncthreads();
    if (tid < OUTc) {
        float s = b_lin[tid];
        for (int k = 0; k < Hc; ++k) s += red[tid][k];
        out[row * OUTc + tid] = s;
    }
}

extern "C" void kernel_launch(void* const* d_in, const int* in_sizes, int n_in,
                              void* d_out, int out_size, void* d_ws, size_t ws_size,
                              hipStream_t stream) {
    const int*   inputs    = (const int*)d_in[0];
    const float* emb_table = (const float*)d_in[1];
    const float* W_ih      = (const float*)d_in[2];
    const float* W_hh      = (const float*)d_in[3];
    const float* b_ih      = (const float*)d_in[4];
    const float* b_hh      = (const float*)d_in[5];
    const float* W_lin     = (const float*)d_in[6];
    const float* b_lin     = (const float*)d_in[7];
    float* out = (float*)d_out;

    rnn_fused<<<Bc, 256, 0, stream>>>(inputs, emb_table, W_ih, W_hh,
                                      b_ih, b_hh, W_lin, b_lin, out);
}

// Round 3
// 509.342 us; speedup vs baseline: 1.9103x; 1.9103x over previous
//
#include <hip/hip_runtime.h>

// RNN: B=1024, T=512, E=64, H=128, OUT=2, VOCAB=4411
// R3:
//  (a) Weights FORCED into VGPRs via empty inline-asm register pins.
//      R1 (VGPR=128) and R2 (VGPR=64) both show the compiler sinking the
//      loop-invariant weight loads into the t-loop; the "+v" asm barrier
//      makes the loaded values opaquely live so they must stay in registers.
//      amdgpu_waves_per_eu(2,2) pins the allocator budget at 256 VGPR.
//  (b) Input projection precomputed PER VOCAB ENTRY (4411 x 128 = 2.26 MB in
//      d_ws, L2-resident): proj_emb[v][j] = emb[v].W_ih[j] + b_ih[j] + b_hh[j].
//      The recurrence step then does 1 coalesced gather instead of 64 FMAs.
//  (c) No p-split: 128 threads/block, thread j owns hidden unit j. h reads
//      are pure 64-lane broadcasts (conflict-free); h writes stride-1.
//      pe gather for step t+1 prefetched during step t's dot product.

constexpr int Bc    = 1024;
constexpr int Tc    = 512;
constexpr int Ec    = 64;
constexpr int Hc    = 128;
constexpr int OUTc  = 2;
constexpr int VOCAB = 4411;

// ---------------- Kernel 1: per-vocab input projection ----------------
__global__ __launch_bounds__(Hc) void pe_kernel(
    const float* __restrict__ emb,   // [VOCAB, E]
    const float* __restrict__ W_ih,  // [H, E]
    const float* __restrict__ b_ih,  // [H]
    const float* __restrict__ b_hh,  // [H]
    float* __restrict__ pe)          // [VOCAB, H]
{
    const int v = blockIdx.x;
    const int j = threadIdx.x;
    const float* er = emb + v * Ec;     // broadcast across threads (L1-hot)
    const float* wr = W_ih + j * Ec;
    float a0 = b_ih[j] + b_hh[j], a1 = 0.f, a2 = 0.f, a3 = 0.f;
#pragma unroll
    for (int e = 0; e < Ec; e += 4) {
        const float4 E = *(const float4*)(er + e);
        const float4 W = *(const float4*)(wr + e);
        a0 = fmaf(E.x, W.x, a0);
        a1 = fmaf(E.y, W.y, a1);
        a2 = fmaf(E.z, W.z, a2);
        a3 = fmaf(E.w, W.w, a3);
    }
    pe[v * Hc + j] = (a0 + a1) + (a2 + a3);
}

// ---------------- Kernel 2: fused recurrence + head ----------------
template <bool USE_PE>
__global__ __attribute__((amdgpu_flat_work_group_size(Hc, Hc),
                          amdgpu_waves_per_eu(2, 2)))
void rnn_kernel(
    const int* __restrict__ inputs,      // [B, T]
    const float* __restrict__ pe,        // [VOCAB, H] (USE_PE) or nullptr
    const float* __restrict__ emb,       // fallback path
    const float* __restrict__ W_ih,      // fallback path
    const float* __restrict__ W_hh,      // [H, H]
    const float* __restrict__ b_ih,
    const float* __restrict__ b_hh,
    const float* __restrict__ W_lin,     // [OUT, H]
    const float* __restrict__ b_lin,     // [OUT]
    float* __restrict__ out)             // [B, OUT]
{
    const int j   = threadIdx.x;  // hidden unit 0..127
    const int row = blockIdx.x;

    __shared__ float h_buf[2][Hc];
    __shared__ int   toks[Tc];
    __shared__ float red[OUTc * Hc];

    for (int i = j; i < Tc; i += Hc) toks[i] = inputs[row * Tc + i];

    // W_hh row j -> 32 float4 in registers, PINNED so the loads cannot be
    // sunk into the t-loop and the values cannot be rematerialized.
    float4 w[Hc / 4];
#pragma unroll
    for (int i = 0; i < Hc / 4; ++i)
        w[i] = *(const float4*)(W_hh + j * Hc + i * 4);
#pragma unroll
    for (int i = 0; i < Hc / 4; ++i)
        asm volatile("" : "+v"(w[i].x), "+v"(w[i].y), "+v"(w[i].z), "+v"(w[i].w));

    float4 wi[Ec / 4];
    float  bias = 0.f;
    if (!USE_PE) {
#pragma unroll
        for (int i = 0; i < Ec / 4; ++i)
            wi[i] = *(const float4*)(W_ih + j * Ec + i * 4);
#pragma unroll
        for (int i = 0; i < Ec / 4; ++i)
            asm volatile("" : "+v"(wi[i].x), "+v"(wi[i].y), "+v"(wi[i].z), "+v"(wi[i].w));
        bias = b_ih[j] + b_hh[j];
    }

    h_buf[0][j] = 0.0f;
    __syncthreads();

    float xp = 0.f;
    if (USE_PE) xp = pe[toks[0] * Hc + j];   // x_proj for t=0 (incl. biases)

    int   cur = 0;
    float hn  = 0.0f;
    for (int t = 0; t < Tc; ++t) {
        // Prefetch next step's projection row while we do this step's dot.
        float xp_next = 0.f;
        if (USE_PE) {
            const int tn = toks[(t + 1 < Tc) ? (t + 1) : t];
            xp_next = pe[tn * Hc + j];       // coalesced 4B/lane, L2-resident
        }

        float a0, a1, a2, a3;
        if (USE_PE) {
            a0 = xp; a1 = 0.f; a2 = 0.f; a3 = 0.f;
        } else {
            a0 = bias; a1 = 0.f; a2 = 0.f; a3 = 0.f;
            const float* er = emb + (long)toks[t] * Ec;
#pragma unroll
            for (int e = 0; e < Ec / 4; ++e) {
                const float4 E = *(const float4*)(er + 4 * e);
                a0 = fmaf(E.x, wi[e].x, a0);
                a1 = fmaf(E.y, wi[e].y, a1);
                a2 = fmaf(E.z, wi[e].z, a2);
                a3 = fmaf(E.w, wi[e].w, a3);
            }
        }

        // Recurrence dot: 64-lane BROADCAST LDS reads (conflict-free).
        const float* hb = h_buf[cur];
#pragma unroll
        for (int k = 0; k < Hc / 4; ++k) {
            const float4 hv = *(const float4*)(hb + 4 * k);
            a0 = fmaf(hv.x, w[k].x, a0);
            a1 = fmaf(hv.y, w[k].y, a1);
            a2 = fmaf(hv.z, w[k].z, a2);
            a3 = fmaf(hv.w, w[k].w, a3);
        }

        const float z  = (a0 + a1) + (a2 + a3);
        const float ex = __expf(2.0f * z);    // tanh via exp, exact at sat
        hn = 1.0f - 2.0f / (ex + 1.0f);

        cur ^= 1;
        h_buf[cur][j] = hn;                   // stride-1, conflict-free
        __syncthreads();
        xp = xp_next;
    }

    // Linear head
    red[j]      = hn * W_lin[j];
    red[Hc + j] = hn * W_lin[Hc + j];
    __syncthreads();
    if (j < OUTc) {
        float s = b_lin[j];
        for (int k = 0; k < Hc; ++k) s += red[j * Hc + k];
        out[row * OUTc + j] = s;
    }
}

extern "C" void kernel_launch(void* const* d_in, const int* in_sizes, int n_in,
                              void* d_out, int out_size, void* d_ws, size_t ws_size,
                              hipStream_t stream) {
    const int*   inputs    = (const int*)d_in[0];
    const float* emb_table = (const float*)d_in[1];
    const float* W_ih      = (const float*)d_in[2];
    const float* W_hh      = (const float*)d_in[3];
    const float* b_ih      = (const float*)d_in[4];
    const float* b_hh      = (const float*)d_in[5];
    const float* W_lin     = (const float*)d_in[6];
    const float* b_lin     = (const float*)d_in[7];
    float* out = (float*)d_out;

    const size_t pe_bytes = (size_t)VOCAB * Hc * sizeof(float);
    if (ws_size >= pe_bytes) {
        float* pe = (float*)d_ws;
        pe_kernel<<<VOCAB, Hc, 0, stream>>>(emb_table, W_ih, b_ih, b_hh, pe);
        rnn_kernel<true><<<Bc, Hc, 0, stream>>>(inputs, pe, emb_table, W_ih,
                                                W_hh, b_ih, b_hh, W_lin, b_lin, out);
    } else {
        rnn_kernel<false><<<Bc, Hc, 0, stream>>>(inputs, nullptr, emb_table, W_ih,
                                                 W_hh, b_ih, b_hh, W_lin, b_lin, out);
    }
}